// Round 1
// baseline (103.454 us; speedup 1.0000x reference)
//
#include <hip/hip_runtime.h>

#define G 8192
#define IMG_W 512
#define IMG_H 512
#define TILE 16
#define NTX (IMG_W / TILE)
#define NTY (IMG_H / TILE)
#define BLK 256
#define CAP 1024            // per-tile list capacity (avg ~190)
#define ALPHA_THRESH (1.0f/255.0f)
#define ALPHA_CAP 0.99f
#define TRANS_THRESH 1e-4f

// -----------------------------------------------------------------------
// Kernel 0: per-gaussian tile-span, packed into ONE u32 (txmin,txmax,
// tymin,tymax as bytes). alpha = op*exp(-sigma) >= 1/255 requires
// sigma <= smax = ln(255*op); tight ellipse AABB half-extents are
// sqrt(2*smax*(A^-1)_ii), inflated (x1.0001 + 0.01px) so float rounding
// can never cause a false exclusion -> culling is exact.
// -----------------------------------------------------------------------
__global__ __launch_bounds__(BLK)
void range_kernel(const float* __restrict__ means2d,
                  const float* __restrict__ conics,
                  const float* __restrict__ opac,
                  unsigned int* __restrict__ ranges)
{
    int g = blockIdx.x * BLK + threadIdx.x;
    if (g >= G) return;
    float op = opac[g];
    unsigned int packed = 0xFFu;          // default: culled
    if (op * 255.0f >= 1.0f) {
        float smax = __logf(op * 255.0f);
        float a = conics[3*g], b = conics[3*g+1], c = conics[3*g+2];
        float det = fmaxf(a * c - b * b, 1e-12f);
        float rx = sqrtf(fmaxf(2.0f * smax * c / det, 0.0f)) * 1.0001f + 0.01f;
        float ry = sqrtf(fmaxf(2.0f * smax * a / det, 0.0f)) * 1.0001f + 0.01f;
        float mx = means2d[2*g], my = means2d[2*g+1];
        int txmin = (int)ceilf ((mx - rx - 15.5f) * 0.0625f);
        int txmax = (int)floorf((mx + rx -  0.5f) * 0.0625f);
        int tymin = (int)ceilf ((my - ry - 15.5f) * 0.0625f);
        int tymax = (int)floorf((my + ry -  0.5f) * 0.0625f);
        if (!(txmax < 0 || txmin > NTX-1 || tymax < 0 || tymin > NTY-1 ||
              txmin > txmax || tymin > tymax)) {
            txmin = max(txmin, 0); txmax = min(txmax, NTX-1);
            tymin = max(tymin, 0); tymax = min(tymax, NTY-1);
            packed = (unsigned)txmin | ((unsigned)txmax << 8)
                   | ((unsigned)tymin << 16) | ((unsigned)tymax << 24);
        }
    }
    ranges[g] = packed;
}

__device__ __forceinline__ int hitp(unsigned p, unsigned btx, unsigned bty)
{
    return (btx >= (p & 0xffu)) & (btx <= ((p >> 8) & 0xffu)) &
           (bty >= ((p >> 16) & 0xffu)) & (bty <= (p >> 24));
}

// uniform cross-lane broadcast on the VALU pipe (v_readlane -> SGPR),
// replacing per-gaussian LDS broadcast reads (CU-shared DS pipe).
__device__ __forceinline__ float rl(float v, int l)
{
    return __uint_as_float(__builtin_amdgcn_readlane(__float_as_uint(v),
                                                     (unsigned)l));
}

// -----------------------------------------------------------------------
// Kernel 1 (one block per 16x16 tile):
//  Phase 1: barrier-free two-pass scan (registers hold the 32KB range
//           table slice), ballot compaction in gaussian-index order.
//  Phase 2: rank sort with 32-bit float-bit keys; stability via the
//           POSITION tiebreak (pre-sort list is idx-ordered, so j<i is
//           exactly the idx tiebreak). Halves sort DS traffic vs 64-bit.
//  Phase 3: per-wave register broadcast. Groups of 64 gaussians: each
//           lane gathers one gaussian's 9 floats from global (L2-hot),
//           inner loop broadcasts lane j's registers via v_readlane.
//           Zero LDS traffic, zero __syncthreads, per-wave early exit.
// -----------------------------------------------------------------------
__global__ __launch_bounds__(BLK)
void tile_kernel(const unsigned int* __restrict__ ranges,
                 const float* __restrict__ depths,
                 const float* __restrict__ means2d,
                 const float* __restrict__ conics,
                 const float* __restrict__ colors,
                 const float* __restrict__ opac,
                 float*       __restrict__ out)
{
    __shared__ unsigned short slist[CAP];
    __shared__ unsigned int   fkeys[CAP];
    __shared__ int woff[4];

    const int tx = threadIdx.x, ty = threadIdx.y;
    const int t = ty * TILE + tx;
    const int lane = t & 63, w = t >> 6;
    const unsigned btx = blockIdx.x, bty = blockIdx.y;

    // ---- Phase 1, pass A: load + count (no barriers) ----
    const uint4* r4 = (const uint4*)ranges;
    const int wbase = w * (G / 4);            // 2048 gaussians per wave
    uint4 rv[8];
    #pragma unroll
    for (int i = 0; i < 8; ++i)
        rv[i] = r4[(wbase >> 2) + i * 64 + lane];

    int cnt = 0;
    #pragma unroll
    for (int i = 0; i < 8; ++i)
        cnt += hitp(rv[i].x, btx, bty) + hitp(rv[i].y, btx, bty)
             + hitp(rv[i].z, btx, bty) + hitp(rv[i].w, btx, bty);
    #pragma unroll
    for (int d = 1; d < 64; d <<= 1) cnt += __shfl_xor(cnt, d);
    if (lane == 0) woff[w] = cnt;
    __syncthreads();

    int offs = 0;
    for (int ww = 0; ww < w; ++ww) offs += woff[ww];
    const int N = min(woff[0] + woff[1] + woff[2] + woff[3], CAP);

    // ---- Phase 1, pass B: ballot compaction ----
    const unsigned long long lt = (1ull << lane) - 1ull;
    #pragma unroll
    for (int i = 0; i < 8; ++i) {
        int gbase = wbase + i * 256 + lane * 4;
        int h0 = hitp(rv[i].x, btx, bty), h1 = hitp(rv[i].y, btx, bty);
        int h2 = hitp(rv[i].z, btx, bty), h3 = hitp(rv[i].w, btx, bty);
        unsigned long long m0 = __ballot(h0), m1 = __ballot(h1);
        unsigned long long m2 = __ballot(h2), m3 = __ballot(h3);
        int pos = offs + __popcll(m0 & lt) + __popcll(m1 & lt)
                       + __popcll(m2 & lt) + __popcll(m3 & lt);
        if (h0) { if (pos < CAP) slist[pos] = (unsigned short)(gbase    ); pos++; }
        if (h1) { if (pos < CAP) slist[pos] = (unsigned short)(gbase + 1); pos++; }
        if (h2) { if (pos < CAP) slist[pos] = (unsigned short)(gbase + 2); pos++; }
        if (h3) { if (pos < CAP) slist[pos] = (unsigned short)(gbase + 3); pos++; }
        offs += __popcll(m0) + __popcll(m1) + __popcll(m2) + __popcll(m3);
    }
    __syncthreads();

    // ---- Phase 2: rank sort, 32-bit keys + position tiebreak ----
    unsigned short myidx[4]; unsigned int mykey[4]; int myr[4];
    #pragma unroll
    for (int m = 0; m < 4; ++m) {
        int i = t + m * BLK;
        if (i < N) {
            unsigned idx = slist[i];
            unsigned k = __float_as_uint(depths[idx]);   // depths > 0
            myidx[m] = (unsigned short)idx; mykey[m] = k; fkeys[i] = k;
        }
    }
    __syncthreads();
    #pragma unroll
    for (int m = 0; m < 4; ++m) {
        int i = t + m * BLK;
        if (i < N) {
            unsigned ke = mykey[m]; int r = 0;
            #pragma unroll 4
            for (int j = 0; j < N; ++j) {
                unsigned kj = fkeys[j];
                r += (int)((kj < ke) | ((kj == ke) & (j < i)));
            }
            myr[m] = r;
        }
    }
    __syncthreads();
    #pragma unroll
    for (int m = 0; m < 4; ++m) {
        int i = t + m * BLK;
        if (i < N) slist[myr[m]] = myidx[m];
    }
    __syncthreads();

    // ---- Phase 3: composite (per-wave, register broadcast) ----
    const float px = (float)(btx * TILE + tx) + 0.5f;
    const float py = (float)(bty * TILE + ty) + 0.5f;
    float T = 1.0f, accr = 0.0f, accg = 0.0f, accb = 0.0f;

    for (int base = 0; base < N; base += 64) {
        int nn = min(64, N - base);
        // lane l stages gaussian slist[base+l]; pad lanes reuse slist[base]
        // with op=0 -> exact no-op (sigma finite >= 0, alpha 0).
        int ll = (lane < nn) ? lane : 0;
        int idx = slist[base + ll];
        float mx = means2d[2*idx], my = means2d[2*idx+1];
        float ha = conics[3*idx]   * 0.5f;       // fold the 0.5 once
        float hb = conics[3*idx+1];
        float hc = conics[3*idx+2] * 0.5f;
        float op = (lane < nn) ? opac[idx] : 0.0f;
        float cr = colors[3*idx], cg = colors[3*idx+1], cbl = colors[3*idx+2];

        int nn4 = (nn + 3) & ~3;
        bool fin = false;
        for (int j = 0; j < nn4; j += 4) {
            #pragma unroll
            for (int u = 0; u < 4; ++u) {
                int l = j + u;                   // l<64 always; pads are no-ops
                float smx = rl(mx, l), smy = rl(my, l);
                float sa  = rl(ha, l), sb  = rl(hb, l), sc = rl(hc, l);
                float sop = rl(op, l);
                float dx = px - smx, dy = py - smy;
                float sig = fmaf(sa, dx*dx, fmaf(sc, dy*dy, sb * (dx*dy)));
                float al = sop * __expf(-sig);
                bool ok = (sig >= 0.0f) && (al >= ALPHA_THRESH);
                al = ok ? fminf(al, ALPHA_CAP) : 0.0f;
                float wgt = al * T;
                accr = fmaf(wgt, rl(cr, l),  accr);
                accg = fmaf(wgt, rl(cg, l),  accg);
                accb = fmaf(wgt, rl(cbl, l), accb);
                T *= (1.0f - al);                // matches reference rounding
            }
            // wave-uniform deferred exit: residual contributions telescope
            // to <= T < 1e-4 per channel -> within tolerance.
            if (__all(T < TRANS_THRESH)) { fin = true; break; }
        }
        if (fin) break;
    }

    const int o = (((int)bty * TILE + ty) * IMG_W + (int)btx * TILE + tx) * 3;
    out[o]     = accr;
    out[o + 1] = accg;
    out[o + 2] = accb;   // BG = 0 -> t_rem term vanishes
}

extern "C" void kernel_launch(void* const* d_in, const int* in_sizes, int n_in,
                              void* d_out, int out_size, void* d_ws, size_t ws_size,
                              hipStream_t stream)
{
    const float* means2d = (const float*)d_in[0];  // (G,2)
    const float* conics  = (const float*)d_in[1];  // (G,3)
    const float* colors  = (const float*)d_in[2];  // (G,3)
    const float* opac    = (const float*)d_in[3];  // (G,)
    const float* depths  = (const float*)d_in[4];  // (G,)
    float* out = (float*)d_out;
    unsigned int* ranges = (unsigned int*)d_ws;    // G u32 = 32 KB of ws

    range_kernel<<<G / BLK, BLK, 0, stream>>>(means2d, conics, opac, ranges);
    tile_kernel<<<dim3(NTX, NTY), dim3(TILE, TILE), 0, stream>>>(
        ranges, depths, means2d, conics, colors, opac, out);
}

// Round 2
// 94.699 us; speedup vs baseline: 1.0925x; 1.0925x over previous
//
#include <hip/hip_runtime.h>

#define G 8192
#define IMG_W 512
#define IMG_H 512
#define TILE 16
#define NTX (IMG_W / TILE)
#define NTY (IMG_H / TILE)
#define BLK 256
#define CAP 1024            // per-tile list capacity (avg ~190)
#define ALPHA_THRESH (1.0f/255.0f)
#define ALPHA_CAP 0.99f
#define TRANS_THRESH 1e-4f

// -----------------------------------------------------------------------
// Kernel 0: per-gaussian tile-span (exact conservative cull, packed u32)
// PLUS a packed 64B record per gaussian:
//   r[0]=mx r[1]=my r[2]=0.5a r[3]=b r[4]=0.5c r[5]=op r[6..8]=rgb
// Record G (index 8192) is all-zero: op=0 -> exact no-op pad gaussian.
// -----------------------------------------------------------------------
__global__ __launch_bounds__(BLK)
void range_kernel(const float* __restrict__ means2d,
                  const float* __restrict__ conics,
                  const float* __restrict__ colors,
                  const float* __restrict__ opac,
                  unsigned int* __restrict__ ranges,
                  float* __restrict__ tbl)
{
    int g = blockIdx.x * BLK + threadIdx.x;
    if (g >= G) return;
    float op = opac[g];
    float a  = conics[3*g], b = conics[3*g+1], c = conics[3*g+2];
    float mx = means2d[2*g], my = means2d[2*g+1];
    float cr = colors[3*g], cg = colors[3*g+1], cb = colors[3*g+2];

    float4* t4 = (float4*)(tbl + (g << 4));
    t4[0] = make_float4(mx, my, 0.5f * a, b);
    t4[1] = make_float4(0.5f * c, op, cr, cg);
    t4[2] = make_float4(cb, 0.0f, 0.0f, 0.0f);
    if (g == 0) {                       // zero pad-record at index G
        float4* z = (float4*)(tbl + (G << 4));
        z[0] = z[1] = z[2] = make_float4(0.0f, 0.0f, 0.0f, 0.0f);
    }

    unsigned int packed = 0xFFu;          // default: culled
    if (op * 255.0f >= 1.0f) {
        float smax = __logf(op * 255.0f);
        float det = fmaxf(a * c - b * b, 1e-12f);
        float rx = sqrtf(fmaxf(2.0f * smax * c / det, 0.0f)) * 1.0001f + 0.01f;
        float ry = sqrtf(fmaxf(2.0f * smax * a / det, 0.0f)) * 1.0001f + 0.01f;
        int txmin = (int)ceilf ((mx - rx - 15.5f) * 0.0625f);
        int txmax = (int)floorf((mx + rx -  0.5f) * 0.0625f);
        int tymin = (int)ceilf ((my - ry - 15.5f) * 0.0625f);
        int tymax = (int)floorf((my + ry -  0.5f) * 0.0625f);
        if (!(txmax < 0 || txmin > NTX-1 || tymax < 0 || tymin > NTY-1 ||
              txmin > txmax || tymin > tymax)) {
            txmin = max(txmin, 0); txmax = min(txmax, NTX-1);
            tymin = max(tymin, 0); tymax = min(tymax, NTY-1);
            packed = (unsigned)txmin | ((unsigned)txmax << 8)
                   | ((unsigned)tymin << 16) | ((unsigned)tymax << 24);
        }
    }
    ranges[g] = packed;
}

__device__ __forceinline__ int hitp(unsigned p, unsigned btx, unsigned bty)
{
    return (btx >= (p & 0xffu)) & (btx <= ((p >> 8) & 0xffu)) &
           (bty >= ((p >> 16) & 0xffu)) & (bty <= (p >> 24));
}

// -----------------------------------------------------------------------
// Kernel 1 (one block per 16x16 tile):
//  Phase 1: barrier-free two-pass scan + ballot compaction (idx order).
//  Phase 2: rank sort, 32-bit float-bit keys, POSITION tiebreak (list is
//           idx-ordered so j<i == idx tiebreak); keys read as uint4 ->
//           1 ds_read_b128 per 4 comparisons.
//  Phase 3: wave-uniform SCALAR-PIPE compositing. Sorted idx is made
//           known-uniform via readfirstlane; the 64B record loads become
//           s_load_dwordx* on the SMEM pipe (idle otherwise) — no LDS
//           broadcast (DS pipe freed), no readlane VALU/hazard cost, no
//           barriers (per-wave __all early exit). Tail padded with the
//           zero record (index G) -> branchless groups of 4.
// -----------------------------------------------------------------------
__global__ __launch_bounds__(BLK)
void tile_kernel(const unsigned int* __restrict__ ranges,
                 const float* __restrict__ depths,
                 const float* __restrict__ tbl,
                 float*       __restrict__ out)
{
    __shared__ unsigned short slist[CAP + 4];
    __shared__ __align__(16) unsigned int fkeys[CAP + 4];
    __shared__ int woff[4];

    const int tx = threadIdx.x, ty = threadIdx.y;
    const int t = ty * TILE + tx;
    const int lane = t & 63, w = t >> 6;
    const unsigned btx = blockIdx.x, bty = blockIdx.y;

    // ---- Phase 1, pass A: load + count (no barriers) ----
    const uint4* r4 = (const uint4*)ranges;
    const int wbase = w * (G / 4);            // 2048 gaussians per wave
    uint4 rv[8];
    #pragma unroll
    for (int i = 0; i < 8; ++i)
        rv[i] = r4[(wbase >> 2) + i * 64 + lane];

    int cnt = 0;
    #pragma unroll
    for (int i = 0; i < 8; ++i)
        cnt += hitp(rv[i].x, btx, bty) + hitp(rv[i].y, btx, bty)
             + hitp(rv[i].z, btx, bty) + hitp(rv[i].w, btx, bty);
    #pragma unroll
    for (int d = 1; d < 64; d <<= 1) cnt += __shfl_xor(cnt, d);
    if (lane == 0) woff[w] = cnt;
    __syncthreads();

    int offs = 0;
    for (int ww = 0; ww < w; ++ww) offs += woff[ww];
    const int N = min(woff[0] + woff[1] + woff[2] + woff[3], CAP);

    // ---- Phase 1, pass B: ballot compaction ----
    const unsigned long long lt = (1ull << lane) - 1ull;
    #pragma unroll
    for (int i = 0; i < 8; ++i) {
        int gbase = wbase + i * 256 + lane * 4;
        int h0 = hitp(rv[i].x, btx, bty), h1 = hitp(rv[i].y, btx, bty);
        int h2 = hitp(rv[i].z, btx, bty), h3 = hitp(rv[i].w, btx, bty);
        unsigned long long m0 = __ballot(h0), m1 = __ballot(h1);
        unsigned long long m2 = __ballot(h2), m3 = __ballot(h3);
        int pos = offs + __popcll(m0 & lt) + __popcll(m1 & lt)
                       + __popcll(m2 & lt) + __popcll(m3 & lt);
        if (h0) { if (pos < CAP) slist[pos] = (unsigned short)(gbase    ); pos++; }
        if (h1) { if (pos < CAP) slist[pos] = (unsigned short)(gbase + 1); pos++; }
        if (h2) { if (pos < CAP) slist[pos] = (unsigned short)(gbase + 2); pos++; }
        if (h3) { if (pos < CAP) slist[pos] = (unsigned short)(gbase + 3); pos++; }
        offs += __popcll(m0) + __popcll(m1) + __popcll(m2) + __popcll(m3);
    }
    __syncthreads();

    // ---- Phase 2: rank sort, 32-bit keys + position tiebreak ----
    unsigned short myidx[4]; unsigned int mykey[4]; int myr[4];
    #pragma unroll
    for (int m = 0; m < 4; ++m) {
        int i = t + m * BLK;
        if (i < N) {
            unsigned idx = slist[i];
            unsigned k = __float_as_uint(depths[idx]);   // depths > 0
            myidx[m] = (unsigned short)idx; mykey[m] = k; fkeys[i] = k;
        }
    }
    if (t < 4) fkeys[N + t] = 0xFFFFFFFFu;   // pad: never counts as "<"
    __syncthreads();

    const uint4* fk4 = (const uint4*)fkeys;
    const int nj4 = (N + 3) >> 2;
    #pragma unroll
    for (int m = 0; m < 4; ++m) {
        int i = t + m * BLK;
        if (i < N) {
            unsigned ke = mykey[m]; int r = 0;
            for (int j4 = 0; j4 < nj4; ++j4) {
                uint4 kv = fk4[j4]; int j = j4 << 2;
                r += (int)((kv.x < ke) | ((kv.x == ke) & (j     < i)));
                r += (int)((kv.y < ke) | ((kv.y == ke) & (j + 1 < i)));
                r += (int)((kv.z < ke) | ((kv.z == ke) & (j + 2 < i)));
                r += (int)((kv.w < ke) | ((kv.w == ke) & (j + 3 < i)));
            }
            myr[m] = r;
        }
    }
    __syncthreads();
    #pragma unroll
    for (int m = 0; m < 4; ++m) {
        int i = t + m * BLK;
        if (i < N) slist[myr[m]] = myidx[m];
    }
    if (t < 4) slist[N + t] = (unsigned short)G;   // pad -> zero record
    __syncthreads();

    // ---- Phase 3: composite (scalar-pipe records, barrier-free) ----
    const float px = (float)(btx * TILE + tx) + 0.5f;
    const float py = (float)(bty * TILE + ty) + 0.5f;
    float T = 1.0f, accr = 0.0f, accg = 0.0f, accb = 0.0f;

    for (int base = 0; base < N; base += 4) {
        ushort4 s4 = *(const ushort4*)&slist[base];   // 1 ds_read_b64 / 4
        unsigned short sv[4] = { s4.x, s4.y, s4.z, s4.w };
        #pragma unroll
        for (int u = 0; u < 4; ++u) {
            // wave-uniform index -> record loads go to the SMEM pipe
            int idx = __builtin_amdgcn_readfirstlane((int)sv[u]);
            const float* r = tbl + (idx << 4);
            float dx = px - r[0], dy = py - r[1];
            float sig = fmaf(r[2], dx*dx, fmaf(r[4], dy*dy, r[3] * (dx*dy)));
            float al = r[5] * __expf(-sig);
            bool ok = (sig >= 0.0f) && (al >= ALPHA_THRESH);
            al = ok ? fminf(al, ALPHA_CAP) : 0.0f;
            float wgt = al * T;
            accr = fmaf(wgt, r[6], accr);
            accg = fmaf(wgt, r[7], accg);
            accb = fmaf(wgt, r[8], accb);
            T *= (1.0f - al);                // matches reference rounding
        }
        // per-wave deferred exit: residual contributions telescope to
        // <= T < 1e-4 per channel -> within tolerance. No barriers.
        if (__all(T < TRANS_THRESH)) break;
    }

    const int o = (((int)bty * TILE + ty) * IMG_W + (int)btx * TILE + tx) * 3;
    out[o]     = accr;
    out[o + 1] = accg;
    out[o + 2] = accb;   // BG = 0 -> t_rem term vanishes
}

extern "C" void kernel_launch(void* const* d_in, const int* in_sizes, int n_in,
                              void* d_out, int out_size, void* d_ws, size_t ws_size,
                              hipStream_t stream)
{
    const float* means2d = (const float*)d_in[0];  // (G,2)
    const float* conics  = (const float*)d_in[1];  // (G,3)
    const float* colors  = (const float*)d_in[2];  // (G,3)
    const float* opac    = (const float*)d_in[3];  // (G,)
    const float* depths  = (const float*)d_in[4];  // (G,)
    float* out = (float*)d_out;
    unsigned int* ranges = (unsigned int*)d_ws;                 // 32 KB
    float* tbl = (float*)((char*)d_ws + 32 * 1024);             // (G+1)*64 B

    range_kernel<<<G / BLK, BLK, 0, stream>>>(means2d, conics, colors, opac,
                                              ranges, tbl);
    tile_kernel<<<dim3(NTX, NTY), dim3(TILE, TILE), 0, stream>>>(
        ranges, depths, tbl, out);
}